// Round 5
// baseline (1137.696 us; speedup 1.0000x reference)
//
#include <hip/hip_runtime.h>
#include <hip/hip_bf16.h>
#include <math.h>

typedef __bf16 bf16;
typedef __bf16 v8bf __attribute__((ext_vector_type(8)));
typedef float v4f __attribute__((ext_vector_type(4)));

#define B_   4
#define S_   2048
#define E_   1024
#define CS_  16
#define NC_  8
#define H_   16
#define D_   1040
#define DH_  65
#define DFF_ 4096
#define M_   8192

__device__ __forceinline__ v4f mfma16(v8bf a, v8bf b, v4f c) {
    return __builtin_amdgcn_mfma_f32_16x16x32_bf16(a, b, c, 0, 0, 0);
}

__device__ __forceinline__ void async16(const bf16* g, bf16* l) {
    __builtin_amdgcn_global_load_lds(
        (const __attribute__((address_space(1))) unsigned int*)g,
        (__attribute__((address_space(3))) unsigned int*)l, 16, 0, 0);
}

// ---------------- f32 -> bf16 weight conversion ----------------
__global__ __launch_bounds__(256) void k_cvt(const float* __restrict__ src,
                                             bf16* __restrict__ dst, int n) {
    int i = (blockIdx.x * 256 + threadIdx.x) * 4;
    if (i + 4 <= n) {
        float4 v = *(const float4*)(src + i);
        bf16 o[4] = {(bf16)v.x, (bf16)v.y, (bf16)v.z, (bf16)v.w};
        *(ushort4*)(dst + i) = *(const ushort4*)o;
    }
}

// ---------------- zero qp/kp pad columns (d in [64,96) per row) ----------------
__global__ __launch_bounds__(256) void k_zero_pads(bf16* __restrict__ qp,
                                                   bf16* __restrict__ kp) {
    int i = blockIdx.x * 256 + threadIdx.x;     // 131072 rows * 8 uint4
    int row = i >> 3, j = i & 7;
    uint4 z = {0u, 0u, 0u, 0u};
    bf16* base = (j < 4) ? qp : kp;
    ((uint4*)(base + (size_t)row * 96 + 64))[j & 3] = z;
}

// ---------------- LayerNorm(x f32) + concat cond -> xc (M x D) bf16 ----------------
__global__ __launch_bounds__(256) void k_ln_concat(
    const float* __restrict__ x, const float* __restrict__ cond,
    const float* __restrict__ g, const float* __restrict__ bn,
    bf16* __restrict__ xc)
{
    int row = blockIdx.x;
    int t = threadIdx.x;
    const float* xr = x + (size_t)row * E_;
    float4 v = *(const float4*)(xr + t * 4);
    float s = v.x + v.y + v.z + v.w;
    float ss = v.x * v.x + v.y * v.y + v.z * v.z + v.w * v.w;
#pragma unroll
    for (int off = 32; off; off >>= 1) {
        s  += __shfl_down(s, off);
        ss += __shfl_down(ss, off);
    }
    __shared__ float red[8];
    int wid = t >> 6;
    if ((t & 63) == 0) { red[wid] = s; red[4 + wid] = ss; }
    __syncthreads();
    float stot  = red[0] + red[1] + red[2] + red[3];
    float sstot = red[4] + red[5] + red[6] + red[7];
    float mean = stot * (1.0f / E_);
    float var  = sstot * (1.0f / E_) - mean * mean;
    float rs = rsqrtf(var + 1e-5f);
    bf16* xcr = xc + (size_t)row * D_;
    float vv[4] = {v.x, v.y, v.z, v.w};
#pragma unroll
    for (int j = 0; j < 4; ++j) {
        int i = t * 4 + j;
        xcr[i] = (bf16)(((vv[j] - mean) * rs) * g[i] + bn[i]);
    }
    if (t < CS_) xcr[E_ + t] = (bf16)cond[(size_t)row * CS_ + t];
}

// ---------------- generic full GEMM w/ epilogue (QV, FF1) ----------------
#define EP_QV  0
#define EP_FF1 1

template<int EP>
__global__ __launch_bounds__(256) void k_gemm(
    const bf16* __restrict__ A, const bf16* __restrict__ Bm,
    const float* __restrict__ bias, const float* __restrict__ bias2,
    int M, int N, int K, int lda, int ldb, int nbn,
    bf16* __restrict__ Cb, int ldc, bf16* __restrict__ Cb2)
{
    __shared__ bf16 As[128][32];
    __shared__ bf16 Bs[128][32];
    int t = threadIdx.x;

    int pid = blockIdx.x;
    int nig = 8 * nbn;
    int gid = pid / nig;
    int rem = pid - gid * nig;
    int mi = gid * 8 + (rem & 7);
    int ni = rem >> 3;
    int m0 = mi << 7, n0 = ni << 7;

    int lane = t & 63, w = t >> 6;
    int wm = (w >> 1) * 64, wn = (w & 1) * 64;
    int lr = lane & 15, lq = lane >> 4;

    int row_i[2], seg_i[2];
#pragma unroll
    for (int i = 0; i < 2; ++i) { row_i[i] = (t + i * 256) >> 2; seg_i[i] = (t + i * 256) & 3; }

    v4f acc[4][4];
    v4f vzero = {0.f, 0.f, 0.f, 0.f};
#pragma unroll
    for (int mt = 0; mt < 4; ++mt)
#pragma unroll
        for (int nt = 0; nt < 4; ++nt) acc[mt][nt] = vzero;

    const int KF = K >> 5;
    const bool KR = (K & 31) != 0;

    for (int kb = 0; kb < KF; ++kb) {
        int k0 = kb << 5;
#pragma unroll
        for (int i = 0; i < 2; ++i) {
            async16(A + (size_t)(m0 + row_i[i]) * lda + k0 + seg_i[i] * 8,
                    &As[0][0] + (t + i * 256) * 8);
            async16(Bm + (size_t)(n0 + row_i[i]) * ldb + k0 + seg_i[i] * 8,
                    &Bs[0][0] + (t + i * 256) * 8);
        }
        __syncthreads();
        v8bf af[4], bfr[4];
#pragma unroll
        for (int mt = 0; mt < 4; ++mt) af[mt]  = *(const v8bf*)(&As[wm + mt * 16 + lr][lq * 8]);
#pragma unroll
        for (int nt = 0; nt < 4; ++nt) bfr[nt] = *(const v8bf*)(&Bs[wn + nt * 16 + lr][lq * 8]);
#pragma unroll
        for (int mt = 0; mt < 4; ++mt)
#pragma unroll
            for (int nt = 0; nt < 4; ++nt)
                acc[mt][nt] = mfma16(af[mt], bfr[nt], acc[mt][nt]);
        __syncthreads();
    }
    if (KR) {
        int k0 = KF << 5;
#pragma unroll
        for (int i = 0; i < 2; ++i) {
            int gk = k0 + seg_i[i] * 8;
            uint4 val = {0u, 0u, 0u, 0u};
            if (gk + 8 <= K) val = *(const uint4*)(A + (size_t)(m0 + row_i[i]) * lda + gk);
            *(uint4*)(&As[row_i[i]][seg_i[i] * 8]) = val;
            uint4 bv = {0u, 0u, 0u, 0u};
            int gn = n0 + row_i[i];
            if (gn < N && gk + 8 <= K) bv = *(const uint4*)(Bm + (size_t)gn * ldb + gk);
            *(uint4*)(&Bs[row_i[i]][seg_i[i] * 8]) = bv;
        }
        __syncthreads();
        v8bf af[4], bfr[4];
#pragma unroll
        for (int mt = 0; mt < 4; ++mt) af[mt]  = *(const v8bf*)(&As[wm + mt * 16 + lr][lq * 8]);
#pragma unroll
        for (int nt = 0; nt < 4; ++nt) bfr[nt] = *(const v8bf*)(&Bs[wn + nt * 16 + lr][lq * 8]);
#pragma unroll
        for (int mt = 0; mt < 4; ++mt)
#pragma unroll
            for (int nt = 0; nt < 4; ++nt)
                acc[mt][nt] = mfma16(af[mt], bfr[nt], acc[mt][nt]);
        __syncthreads();
    }

#pragma unroll
    for (int mt = 0; mt < 4; ++mt) {
#pragma unroll
        for (int reg = 0; reg < 4; ++reg) {
            int grow = m0 + wm + mt * 16 + lq * 4 + reg;
#pragma unroll
            for (int nt = 0; nt < 4; ++nt) {
                int gcol = n0 + wn + nt * 16 + lr;
                float vacc = acc[mt][nt][reg];
                if constexpr (EP == EP_QV) {
                    if (gcol < D_) { // Q -> qp padded layout, pre-scaled by log2e/sqrt(65)
                        float o = (vacc + bias[gcol]) * 0.1789442960f;
                        int h = gcol / 65, d = gcol - h * 65;
                        int b = grow >> 11, s = grow & 2047;
                        Cb[(((size_t)(b * 16 + h)) * S_ + s) * 96 + d] = (bf16)o;
                    } else if (gcol < 2 * D_) { // V -> vb row-major
                        int col = gcol - D_;
                        Cb2[(size_t)grow * D_ + col] = (bf16)(vacc + bias2[col]);
                    }
                } else { // EP_FF1
                    float o = vacc + bias[gcol];
                    Cb[(size_t)grow * ldc + gcol] = (bf16)fmaxf(o, 0.f);
                }
            }
        }
    }
}

// ---------------- EP_K split-c partial GEMM: P = sum_{c in [4s,4s+4)} w_c . (xc Wk_c^T) ----------------
__global__ __launch_bounds__(256) void k_gemm_kp(
    const bf16* __restrict__ A, const bf16* __restrict__ Bm,
    const float* __restrict__ condw,
    bf16* __restrict__ P0, bf16* __restrict__ P1)
{
    __shared__ bf16 As[128][32];
    __shared__ bf16 Bs[128][32];
    int t = threadIdx.x;

    int sp = blockIdx.x / 576;
    int pid = blockIdx.x - sp * 576;
    int nig = 72;
    int gid = pid / nig;
    int rem = pid - gid * nig;
    int mi = gid * 8 + (rem & 7);
    int ni = rem >> 3;
    int m0 = mi << 7, n0 = ni << 7;
    bf16* Pout = sp ? P1 : P0;
    int c0 = sp * 4;

    int lane = t & 63, w = t >> 6;
    int wm = (w >> 1) * 64, wn = (w & 1) * 64;
    int lr = lane & 15, lq = lane >> 4;

    int row_i[2], seg_i[2];
#pragma unroll
    for (int i = 0; i < 2; ++i) { row_i[i] = (t + i * 256) >> 2; seg_i[i] = (t + i * 256) & 3; }

    v4f acc[4][4];
    v4f vzero = {0.f, 0.f, 0.f, 0.f};
#pragma unroll
    for (int mt = 0; mt < 4; ++mt)
#pragma unroll
        for (int nt = 0; nt < 4; ++nt) acc[mt][nt] = vzero;

    for (int cc = 0; cc < 4; ++cc) {
        int c = c0 + cc;
        const bf16* Bc = Bm + (size_t)c * D_ * D_;
        float wsc[2];
#pragma unroll
        for (int i = 0; i < 2; ++i) wsc[i] = condw[(size_t)(m0 + row_i[i]) * CS_ + c];
        for (int kb = 0; kb < 33; ++kb) {   // 32 full + 1 remainder (K=1040)
            int k0 = kb << 5;
#pragma unroll
            for (int i = 0; i < 2; ++i) {
                int gk = k0 + seg_i[i] * 8;
                uint4 val = {0u, 0u, 0u, 0u};
                if (gk + 8 <= D_) val = *(const uint4*)(A + (size_t)(m0 + row_i[i]) * D_ + gk);
                union { uint4 u; bf16 h[8]; } u8;
                u8.u = val;
#pragma unroll
                for (int j = 0; j < 8; ++j) u8.h[j] = (bf16)((float)u8.h[j] * wsc[i]);
                *(uint4*)(&As[row_i[i]][seg_i[i] * 8]) = u8.u;
            }
            if (kb < 32) {
#pragma unroll
                for (int i = 0; i < 2; ++i)
                    async16(Bc + (size_t)(n0 + row_i[i]) * D_ + k0 + seg_i[i] * 8,
                            &Bs[0][0] + (t + i * 256) * 8);
            } else {
#pragma unroll
                for (int i = 0; i < 2; ++i) {
                    int gk = k0 + seg_i[i] * 8;
                    uint4 bv = {0u, 0u, 0u, 0u};
                    if (gk + 8 <= D_) bv = *(const uint4*)(Bc + (size_t)(n0 + row_i[i]) * D_ + gk);
                    *(uint4*)(&Bs[row_i[i]][seg_i[i] * 8]) = bv;
                }
            }
            __syncthreads();
            v8bf af[4], bfr[4];
#pragma unroll
            for (int mt = 0; mt < 4; ++mt) af[mt]  = *(const v8bf*)(&As[wm + mt * 16 + lr][lq * 8]);
#pragma unroll
            for (int nt = 0; nt < 4; ++nt) bfr[nt] = *(const v8bf*)(&Bs[wn + nt * 16 + lr][lq * 8]);
#pragma unroll
            for (int mt = 0; mt < 4; ++mt)
#pragma unroll
                for (int nt = 0; nt < 4; ++nt)
                    acc[mt][nt] = mfma16(af[mt], bfr[nt], acc[mt][nt]);
            __syncthreads();
        }
    }

#pragma unroll
    for (int mt = 0; mt < 4; ++mt)
#pragma unroll
        for (int reg = 0; reg < 4; ++reg) {
            int grow = m0 + wm + mt * 16 + lq * 4 + reg;
#pragma unroll
            for (int nt = 0; nt < 4; ++nt) {
                int gcol = n0 + wn + nt * 16 + lr;
                if (gcol < D_)
                    Pout[(size_t)grow * D_ + gcol] = (bf16)acc[mt][nt][reg];
            }
        }
}

// ---------------- K-range-split partial GEMM (O, FF2): raw bf16 partials ----------------
__global__ __launch_bounds__(256) void k_gemm_part(
    const bf16* __restrict__ A, const bf16* __restrict__ Bm,
    int N, int lda, int ldb, int nbn, int bps, int klen0, int klen1,
    bf16* __restrict__ P0, bf16* __restrict__ P1, int ldc)
{
    __shared__ bf16 As[128][32];
    __shared__ bf16 Bs[128][32];
    int t = threadIdx.x;

    int sp = blockIdx.x / bps;
    int pid = blockIdx.x - sp * bps;
    int nig = 8 * nbn;
    int gid = pid / nig;
    int rem = pid - gid * nig;
    int mi = gid * 8 + (rem & 7);
    int ni = rem >> 3;
    int m0 = mi << 7, n0 = ni << 7;
    int koff = sp ? klen0 : 0;
    int K = sp ? klen1 : klen0;
    bf16* Pout = sp ? P1 : P0;

    int lane = t & 63, w = t >> 6;
    int wm = (w >> 1) * 64, wn = (w & 1) * 64;
    int lr = lane & 15, lq = lane >> 4;

    int row_i[2], seg_i[2];
#pragma unroll
    for (int i = 0; i < 2; ++i) { row_i[i] = (t + i * 256) >> 2; seg_i[i] = (t + i * 256) & 3; }

    v4f acc[4][4];
    v4f vzero = {0.f, 0.f, 0.f, 0.f};
#pragma unroll
    for (int mt = 0; mt < 4; ++mt)
#pragma unroll
        for (int nt = 0; nt < 4; ++nt) acc[mt][nt] = vzero;

    const int KF = K >> 5;
    const bool KR = (K & 31) != 0;

    for (int kb = 0; kb < KF; ++kb) {
        int k0 = koff + (kb << 5);
#pragma unroll
        for (int i = 0; i < 2; ++i) {
            async16(A + (size_t)(m0 + row_i[i]) * lda + k0 + seg_i[i] * 8,
                    &As[0][0] + (t + i * 256) * 8);
            async16(Bm + (size_t)(n0 + row_i[i]) * ldb + k0 + seg_i[i] * 8,
                    &Bs[0][0] + (t + i * 256) * 8);
        }
        __syncthreads();
        v8bf af[4], bfr[4];
#pragma unroll
        for (int mt = 0; mt < 4; ++mt) af[mt]  = *(const v8bf*)(&As[wm + mt * 16 + lr][lq * 8]);
#pragma unroll
        for (int nt = 0; nt < 4; ++nt) bfr[nt] = *(const v8bf*)(&Bs[wn + nt * 16 + lr][lq * 8]);
#pragma unroll
        for (int mt = 0; mt < 4; ++mt)
#pragma unroll
            for (int nt = 0; nt < 4; ++nt)
                acc[mt][nt] = mfma16(af[mt], bfr[nt], acc[mt][nt]);
        __syncthreads();
    }
    if (KR) {
        int kl = KF << 5;
#pragma unroll
        for (int i = 0; i < 2; ++i) {
            int gkl = kl + seg_i[i] * 8;
            uint4 val = {0u, 0u, 0u, 0u};
            uint4 bv  = {0u, 0u, 0u, 0u};
            if (gkl + 8 <= K) {
                val = *(const uint4*)(A + (size_t)(m0 + row_i[i]) * lda + koff + gkl);
                bv  = *(const uint4*)(Bm + (size_t)(n0 + row_i[i]) * ldb + koff + gkl);
            }
            *(uint4*)(&As[row_i[i]][seg_i[i] * 8]) = val;
            *(uint4*)(&Bs[row_i[i]][seg_i[i] * 8]) = bv;
        }
        __syncthreads();
        v8bf af[4], bfr[4];
#pragma unroll
        for (int mt = 0; mt < 4; ++mt) af[mt]  = *(const v8bf*)(&As[wm + mt * 16 + lr][lq * 8]);
#pragma unroll
        for (int nt = 0; nt < 4; ++nt) bfr[nt] = *(const v8bf*)(&Bs[wn + nt * 16 + lr][lq * 8]);
#pragma unroll
        for (int mt = 0; mt < 4; ++mt)
#pragma unroll
            for (int nt = 0; nt < 4; ++nt)
                acc[mt][nt] = mfma16(af[mt], bfr[nt], acc[mt][nt]);
        __syncthreads();
    }

#pragma unroll
    for (int mt = 0; mt < 4; ++mt)
#pragma unroll
        for (int reg = 0; reg < 4; ++reg) {
            int grow = m0 + wm + mt * 16 + lq * 4 + reg;
#pragma unroll
            for (int nt = 0; nt < 4; ++nt) {
                int gcol = n0 + wn + nt * 16 + lr;
                if (gcol < N)
                    Pout[(size_t)grow * ldc + gcol] = (bf16)acc[mt][nt][reg];
            }
        }
}

// ---------------- combine K partials + cond*bk bias -> kp padded layout ----------------
__global__ __launch_bounds__(256) void k_comb_k(
    const bf16* __restrict__ P0, const bf16* __restrict__ P1,
    const float* __restrict__ condw, const float* __restrict__ bkp,
    bf16* __restrict__ kp)
{
    int idx = blockIdx.x * 256 + threadIdx.x;   // 8192*1040
    int m = idx / 1040, n = idx - m * 1040;
    float v = (float)P0[idx] + (float)P1[idx];
#pragma unroll
    for (int c = 0; c < NC_; ++c)
        v += condw[(size_t)m * CS_ + c] * bkp[(size_t)c * D_ + n];
    int h = n / 65, d = n - h * 65;
    int b = m >> 11, s = m & 2047;
    kp[(((size_t)(b * 16 + h)) * S_ + s) * 96 + d] = (bf16)v;
}

// ---------------- combine O partials + bias + residual -> hb ----------------
__global__ __launch_bounds__(256) void k_comb_o(
    const bf16* __restrict__ P0, const bf16* __restrict__ P1,
    const float* __restrict__ bo, const bf16* __restrict__ xc,
    bf16* __restrict__ hb)
{
    int idx = blockIdx.x * 256 + threadIdx.x;   // 8192*1024
    int m = idx >> 10, n = idx & 1023;
    float v = (float)P0[idx] + (float)P1[idx] + bo[n] + (float)xc[(size_t)m * D_ + n];
    hb[idx] = (bf16)v;
}

// ---------------- transpose v (M x D bf16) into vt [bh][d(80)][s] ----------------
__global__ __launch_bounds__(256) void k_transpose_v(
    const bf16* __restrict__ v, bf16* __restrict__ vt)
{
    int bh = blockIdx.y, s0 = blockIdx.x * 64;
    int b = bh >> 4, h = bh & 15;
    __shared__ bf16 tile[80][65];
#pragma unroll
    for (int i = 0; i < 20; ++i) {
        int idx = threadIdx.x + i * 256;
        int d = idx % 80, sl = idx / 80;
        bf16 val = (bf16)0.f;
        if (d < DH_) val = v[((size_t)b * S_ + s0 + sl) * D_ + h * DH_ + d];
        tile[d][sl] = val;
    }
    __syncthreads();
#pragma unroll
    for (int i = 0; i < 20; ++i) {
        int idx = threadIdx.x + i * 256;
        int sl = idx % 64, d = idx / 64;
        vt[((size_t)bh * 80 + d) * S_ + s0 + sl] = tile[d][sl];
    }
}

// ---------------- flash attention ----------------
__global__ __launch_bounds__(256) void k_attn(
    const bf16* __restrict__ qp, const bf16* __restrict__ kp,
    const bf16* __restrict__ vt, bf16* __restrict__ o)
{
    int bh = blockIdx.y;
    int s0 = blockIdx.x * 64;
    int b = bh >> 4, h = bh & 15;
    int t = threadIdx.x, lane = t & 63, w = t >> 6;
    int lr = lane & 15, lq = lane >> 4;

    __shared__ bf16 Ks[64][104];
    __shared__ bf16 Vs[80][72];
    __shared__ bf16 QP[64 * 104];

    const bf16* qbase = qp + ((size_t)bh * S_ + s0) * 96;
#pragma unroll
    for (int i = 0; i < 3; ++i) {
        int idx = t + i * 256;
        int row = idx / 12, seg = idx % 12;
        *(uint4*)(&QP[row * 104 + seg * 8]) = *(const uint4*)(qbase + (size_t)row * 96 + seg * 8);
    }
    __syncthreads();
    v8bf qreg[3];
#pragma unroll
    for (int ks = 0; ks < 3; ++ks)
        qreg[ks] = *(const v8bf*)(&QP[(w * 16 + lr) * 104 + ks * 32 + lq * 8]);
    __syncthreads();

    bf16* Ps = &QP[w * (16 * 72)];

    float m_r[4], l_r[4];
    v4f o_acc[5];
    v4f vzero = {0.f, 0.f, 0.f, 0.f};
#pragma unroll
    for (int r = 0; r < 4; ++r) { m_r[r] = -1e30f; l_r[r] = 0.f; }
#pragma unroll
    for (int nt = 0; nt < 5; ++nt) o_acc[nt] = vzero;

    for (int kb = 0; kb < S_ / 64; ++kb) {
        const bf16* kbase = kp + ((size_t)bh * S_ + kb * 64) * 96;
#pragma unroll
        for (int i = 0; i < 3; ++i) {
            int idx = t + i * 256;
            int row = idx / 12, seg = idx % 12;
            *(uint4*)(&Ks[row][seg * 8]) = *(const uint4*)(kbase + (size_t)row * 96 + seg * 8);
        }
#pragma unroll
        for (int i = 0; i < 3; ++i) {
            int idx = t + i * 256;
            if (idx < 640) {
                int d = idx >> 3, seg = idx & 7;
                *(uint4*)(&Vs[d][seg * 8]) =
                    *(const uint4*)(vt + ((size_t)bh * 80 + d) * S_ + kb * 64 + seg * 8);
            }
        }
        __syncthreads();

        v4f sacc[4];
#pragma unroll
        for (int nt = 0; nt < 4; ++nt) sacc[nt] = vzero;
#pragma unroll
        for (int ks = 0; ks < 3; ++ks) {
#pragma unroll
            for (int nt = 0; nt < 4; ++nt) {
                v8bf bk2 = *(const v8bf*)(&Ks[nt * 16 + lr][ks * 32 + lq * 8]);
                sacc[nt] = mfma16(qreg[ks], bk2, sacc[nt]);
            }
        }

        float alpha[4];
#pragma unroll
        for (int r = 0; r < 4; ++r) {
            float mx = fmaxf(fmaxf(sacc[0][r], sacc[1][r]), fmaxf(sacc[2][r], sacc[3][r]));
#pragma unroll
            for (int off = 1; off < 16; off <<= 1) mx = fmaxf(mx, __shfl_xor(mx, off));
            float mnew = fmaxf(m_r[r], mx);
            alpha[r] = __builtin_amdgcn_exp2f(m_r[r] - mnew);
            float ps = 0.f;
#pragma unroll
            for (int nt = 0; nt < 4; ++nt) {
                float p = __builtin_amdgcn_exp2f(sacc[nt][r] - mnew);
                sacc[nt][r] = p;
                ps += p;
            }
#pragma unroll
            for (int off = 1; off < 16; off <<= 1) ps += __shfl_xor(ps, off);
            l_r[r] = l_r[r] * alpha[r] + ps;
            m_r[r] = mnew;
        }

#pragma unroll
        for (int nt = 0; nt < 4; ++nt)
#pragma unroll
            for (int r = 0; r < 4; ++r)
                Ps[(lq * 4 + r) * 72 + nt * 16 + lr] = (bf16)sacc[nt][r];
        asm volatile("s_waitcnt lgkmcnt(0)" ::: "memory");

#pragma unroll
        for (int nt = 0; nt < 5; ++nt)
#pragma unroll
            for (int r = 0; r < 4; ++r) o_acc[nt][r] *= alpha[r];

#pragma unroll
        for (int kt = 0; kt < 2; ++kt) {
            v8bf ap = *(const v8bf*)(&Ps[lr * 72 + kt * 32 + lq * 8]);
#pragma unroll
            for (int nt = 0; nt < 5; ++nt) {
                v8bf bv2 = *(const v8bf*)(&Vs[nt * 16 + lr][kt * 32 + lq * 8]);
                o_acc[nt] = mfma16(ap, bv2, o_acc[nt]);
            }
        }
        __syncthreads();
    }

    float inv[4];
#pragma unroll
    for (int r = 0; r < 4; ++r) inv[r] = 1.0f / l_r[r];
    int token = b * S_ + s0 + w * 16 + lq * 4;
#pragma unroll
    for (int nt = 0; nt < 5; ++nt) {
        int d = nt * 16 + lr;
        if (d < DH_) {
#pragma unroll
            for (int r = 0; r < 4; ++r)
                o[(size_t)(token + r) * D_ + h * DH_ + d] = (bf16)(o_acc[nt][r] * inv[r]);
        }
    }
}

// ---------------- fused FF2-combine + final LayerNorm -> out f32 ----------------
__global__ __launch_bounds__(256) void k_ln_out2(
    const bf16* __restrict__ P0, const bf16* __restrict__ P1,
    const bf16* __restrict__ hb, const float* __restrict__ bf2,
    const float* __restrict__ g, const float* __restrict__ bn,
    float* __restrict__ out)
{
    int row = blockIdx.x;
    int t = threadIdx.x;
    size_t base = (size_t)row * E_ + t * 4;
    union { ushort4 u; bf16 h[4]; } a, bpp, c;
    a.u   = *(const ushort4*)(P0 + base);
    bpp.u = *(const ushort4*)(P1 + base);
    c.u   = *(const ushort4*)(hb + base);
    float vv[4];
#pragma unroll
    for (int j = 0; j < 4; ++j)
        vv[j] = (float)a.h[j] + (float)bpp.h[j] + bf2[t * 4 + j] + (float)c.h[j];
    float s = vv[0] + vv[1] + vv[2] + vv[3];
    float ss = vv[0] * vv[0] + vv[1] * vv[1] + vv[2] * vv[2] + vv[3] * vv[3];
#pragma unroll
    for (int off = 32; off; off >>= 1) {
        s  += __shfl_down(s, off);
        ss += __shfl_down(ss, off);
    }
    __shared__ float red[8];
    int wid = t >> 6;
    if ((t & 63) == 0) { red[wid] = s; red[4 + wid] = ss; }
    __syncthreads();
    float stot  = red[0] + red[1] + red[2] + red[3];
    float sstot = red[4] + red[5] + red[6] + red[7];
    float mean = stot * (1.0f / E_);
    float var  = sstot * (1.0f / E_) - mean * mean;
    float rs = rsqrtf(var + 1e-5f);
    float* outr = out + (size_t)row * E_;
#pragma unroll
    for (int j = 0; j < 4; ++j) {
        int i = t * 4 + j;
        outr[i] = ((vv[j] - mean) * rs) * g[i] + bn[i];
    }
}

// ---------------- launch ----------------
extern "C" void kernel_launch(void* const* d_in, const int* in_sizes, int n_in,
                              void* d_out, int out_size, void* d_ws, size_t ws_size,
                              hipStream_t stream) {
    const float* x    = (const float*)d_in[0];
    const float* cond = (const float*)d_in[1];
    const float* Wq   = (const float*)d_in[2];
    const float* bq   = (const float*)d_in[3];
    const float* Wv   = (const float*)d_in[4];
    const float* bv   = (const float*)d_in[5];
    const float* Wk   = (const float*)d_in[6];
    const float* bk   = (const float*)d_in[7];
    const float* Wo   = (const float*)d_in[8];
    const float* bo   = (const float*)d_in[9];
    const float* g2   = (const float*)d_in[12];
    const float* bn2  = (const float*)d_in[13];
    const float* g1   = (const float*)d_in[10];
    const float* bn1  = (const float*)d_in[11];
    const float* Wf1  = (const float*)d_in[14];
    const float* bf1  = (const float*)d_in[15];
    const float* Wf2  = (const float*)d_in[16];
    const float* bf2  = (const float*)d_in[17];
    float* out = (float*)d_out;

    char* ws = (char*)d_ws;
    bf16* Wqv_b = (bf16*)(ws + 0);           // 4,526,080
    bf16* Wk_b  = (bf16*)(ws + 4526080);     // -> 21,831,680
    bf16* Wo_b  = (bf16*)(ws + 21831680);    // -> 23,994,880
    bf16* Wf1_b = (bf16*)(ws + 23994880);    // -> 32,383,488
    bf16* Wf2_b = (bf16*)(ws + 32383488);    // -> 40,772,096
    bf16*  xc  = (bf16*)(ws + 40772096);     // -> 57,811,456 (17.04 MB)
    bf16*  ob  = (bf16*)(ws + 57811456);     // -> 74,850,816 (17.04 MB)
    bf16*  vb  = (bf16*)(ws + 74850816);     // vb pre-attn / hb post-attn
    bf16*  hb  = (bf16*)(ws + 74850816);     // -> 91,890,176
    bf16*  qp  = (bf16*)(ws + 91890176);     // -> 117,056,000 (25.17 MB)
    bf16*  kp  = (bf16*)(ws + 117056000);    // -> 142,221,824 (25.17 MB)
    bf16*  vtb = (bf16*)(ws + 142221824);    // -> 163,193,344 (20.97 MB)
    bf16*  ff1 = (bf16*)(ws + 91890176);     // FF phase: aliases qp/kp/vtb (67.1 MB)
    // partial buffers (timeline-safe aliases)
    bf16* P0k = ob;                          // K partial 0 (17.04 MB, dead pre-attn)
    bf16* P1k = vtb;                         // K partial 1 (17.04 <= 20.97 MB)
    bf16* P0o = qp;                          // O partial 0 (qp dead post-attn)
    bf16* P1o = kp;                          // O partial 1 (kp dead post-attn)
    bf16* P0f = (bf16*)(ws + 40772096);      // FF2 partial 0 (xc dead)
    bf16* P1f = (bf16*)(ws + 57549312);      // FF2 partial 1 (-> 74,326,528 < hb)

    k_cvt<<<(1081600 / 4 + 255) / 256, 256, 0, stream>>>(Wq, Wqv_b, 1081600);
    k_cvt<<<(1081600 / 4 + 255) / 256, 256, 0, stream>>>(Wv, Wqv_b + 1081600, 1081600);
    k_cvt<<<(8652800 / 4 + 255) / 256, 256, 0, stream>>>(Wk, Wk_b, 8652800);
    k_cvt<<<(1081600 / 4 + 255) / 256, 256, 0, stream>>>(Wo, Wo_b, 1081600);
    k_cvt<<<(4194304 / 4 + 255) / 256, 256, 0, stream>>>(Wf1, Wf1_b, 4194304);
    k_cvt<<<(4194304 / 4 + 255) / 256, 256, 0, stream>>>(Wf2, Wf2_b, 4194304);

    k_ln_concat<<<M_, 256, 0, stream>>>(x, cond, g1, bn1, xc);
    k_zero_pads<<<4096, 256, 0, stream>>>(qp, kp);

    // fused Q+V (N=2080 over 17 n-blocks)
    k_gemm<EP_QV><<<64 * 17, 256, 0, stream>>>(xc, Wqv_b, bq, bv, M_, 2 * D_, D_, D_, D_, 17,
                                               qp, 0, vb);
    // K projection: split-c partials + combine
    k_gemm_kp<<<1152, 256, 0, stream>>>(xc, Wk_b, cond, P0k, P1k);
    k_comb_k<<<(M_ * D_) / 256, 256, 0, stream>>>(P0k, P1k, cond, bk, kp);

    k_transpose_v<<<dim3(S_ / 64, 64), 256, 0, stream>>>(vb, vtb);
    k_attn<<<dim3(S_ / 64, 64), 256, 0, stream>>>(qp, kp, vtb, ob);

    // O projection: K-split partials + combine (adds bias + residual xn)
    k_gemm_part<<<1024, 256, 0, stream>>>(ob, Wo_b, E_, D_, D_, 8, 512, 512, 528,
                                          P0o, P1o, E_);
    k_comb_o<<<(M_ * E_) / 256, 256, 0, stream>>>(P0o, P1o, bo, xc, hb);

    k_gemm<EP_FF1><<<64 * 32, 256, 0, stream>>>(hb, Wf1_b, bf1, nullptr, M_, DFF_, E_, E_, E_, 32,
                                                ff1, DFF_, nullptr);

    // FF2: K-split partials, combined inside the final LayerNorm
    k_gemm_part<<<1024, 256, 0, stream>>>(ff1, Wf2_b, E_, DFF_, DFF_, 8, 512, 2048, 2048,
                                          P0f, P1f, E_);
    k_ln_out2<<<M_, 256, 0, stream>>>(P0f, P1f, hb, bf2, g2, bn2, out);
}

// Round 6
// 1076.779 us; speedup vs baseline: 1.0566x; 1.0566x over previous
//
#include <hip/hip_runtime.h>
#include <hip/hip_bf16.h>
#include <math.h>

typedef __bf16 bf16;
typedef __bf16 v8bf __attribute__((ext_vector_type(8)));
typedef float v4f __attribute__((ext_vector_type(4)));

#define B_   4
#define S_   2048
#define E_   1024
#define CS_  16
#define NC_  8
#define H_   16
#define D_   1040
#define DH_  65
#define DFF_ 4096
#define M_   8192
#define KC_  1056          // padded per-c chunk
#define KH_  (4 * KC_)     // 4224, half-K
#define KB2_ (8 * KC_)     // 8448, B' row length

__device__ __forceinline__ v4f mfma16(v8bf a, v8bf b, v4f c) {
    return __builtin_amdgcn_mfma_f32_16x16x32_bf16(a, b, c, 0, 0, 0);
}

__device__ __forceinline__ void async16(const bf16* g, bf16* l) {
    __builtin_amdgcn_global_load_lds(
        (const __attribute__((address_space(1))) unsigned int*)g,
        (__attribute__((address_space(3))) unsigned int*)l, 16, 0, 0);
}

// ---------------- f32 -> bf16 weight conversion ----------------
__global__ __launch_bounds__(256) void k_cvt(const float* __restrict__ src,
                                             bf16* __restrict__ dst, int n) {
    int i = (blockIdx.x * 256 + threadIdx.x) * 4;
    if (i + 4 <= n) {
        float4 v = *(const float4*)(src + i);
        bf16 o[4] = {(bf16)v.x, (bf16)v.y, (bf16)v.z, (bf16)v.w};
        *(ushort4*)(dst + i) = *(const ushort4*)o;
    }
}

// ---------------- build B' for K-projection: Wk[c][n][j] -> B'[n][c*1056+j] ----------------
__global__ __launch_bounds__(256) void k_build_bk(const float* __restrict__ Wk,
                                                  bf16* __restrict__ Bp) {
    int c = blockIdx.y;
    int idx = blockIdx.x * 256 + threadIdx.x;     // 1040 * 130
    if (idx >= 1040 * 130) return;
    int n = idx / 130, u = idx - n * 130;
    const float* src = Wk + ((size_t)(c * D_ + n)) * D_ + u * 8;
    float4 a = *(const float4*)src;
    float4 b = *(const float4*)(src + 4);
    bf16 o[8] = {(bf16)a.x, (bf16)a.y, (bf16)a.z, (bf16)a.w,
                 (bf16)b.x, (bf16)b.y, (bf16)b.z, (bf16)b.w};
    *(uint4*)(Bp + (size_t)n * KB2_ + c * KC_ + u * 8) = *(const uint4*)o;
}

// ---------------- build half A': A'[m][cc*1056+j] = w[m,coff+cc]*xc[m][j] ----------------
__global__ __launch_bounds__(256) void k_scale_a(const bf16* __restrict__ xc,
                                                 const float* __restrict__ cond,
                                                 int coff, bf16* __restrict__ Ap) {
    int idx = blockIdx.x * 256 + threadIdx.x;     // 8192 * 132
    int m = idx / 132, u = idx - m * 132;
    int j = u * 8;
    float4 w4 = *(const float4*)(cond + (size_t)m * CS_ + coff);
    float wv[4] = {w4.x, w4.y, w4.z, w4.w};
    bf16* dst = Ap + (size_t)m * KH_ + j;
    if (j < D_) {
        union { uint4 u4; bf16 h[8]; } src;
        src.u4 = *(const uint4*)(xc + (size_t)m * D_ + j);
        float xv[8];
#pragma unroll
        for (int e = 0; e < 8; ++e) xv[e] = (float)src.h[e];
#pragma unroll
        for (int cc = 0; cc < 4; ++cc) {
            bf16 o[8];
#pragma unroll
            for (int e = 0; e < 8; ++e) o[e] = (bf16)(xv[e] * wv[cc]);
            *(uint4*)(dst + cc * KC_) = *(const uint4*)o;
        }
    } else {
        uint4 z = {0u, 0u, 0u, 0u};
#pragma unroll
        for (int cc = 0; cc < 4; ++cc) *(uint4*)(dst + cc * KC_) = z;
    }
}

// ---------------- zero qp/kp pad columns (d in [64,96) per row) ----------------
__global__ __launch_bounds__(256) void k_zero_pads(bf16* __restrict__ qp,
                                                   bf16* __restrict__ kp) {
    int i = blockIdx.x * 256 + threadIdx.x;     // 131072 rows * 8 uint4
    int row = i >> 3, j = i & 7;
    uint4 z = {0u, 0u, 0u, 0u};
    bf16* base = (j < 4) ? qp : kp;
    ((uint4*)(base + (size_t)row * 96 + 64))[j & 3] = z;
}

// ---------------- LayerNorm(x f32) + concat cond -> xc (M x D) bf16 ----------------
__global__ __launch_bounds__(256) void k_ln_concat(
    const float* __restrict__ x, const float* __restrict__ cond,
    const float* __restrict__ g, const float* __restrict__ bn,
    bf16* __restrict__ xc)
{
    int row = blockIdx.x;
    int t = threadIdx.x;
    const float* xr = x + (size_t)row * E_;
    float4 v = *(const float4*)(xr + t * 4);
    float s = v.x + v.y + v.z + v.w;
    float ss = v.x * v.x + v.y * v.y + v.z * v.z + v.w * v.w;
#pragma unroll
    for (int off = 32; off; off >>= 1) {
        s  += __shfl_down(s, off);
        ss += __shfl_down(ss, off);
    }
    __shared__ float red[8];
    int wid = t >> 6;
    if ((t & 63) == 0) { red[wid] = s; red[4 + wid] = ss; }
    __syncthreads();
    float stot  = red[0] + red[1] + red[2] + red[3];
    float sstot = red[4] + red[5] + red[6] + red[7];
    float mean = stot * (1.0f / E_);
    float var  = sstot * (1.0f / E_) - mean * mean;
    float rs = rsqrtf(var + 1e-5f);
    bf16* xcr = xc + (size_t)row * D_;
    float vv[4] = {v.x, v.y, v.z, v.w};
#pragma unroll
    for (int j = 0; j < 4; ++j) {
        int i = t * 4 + j;
        xcr[i] = (bf16)(((vv[j] - mean) * rs) * g[i] + bn[i]);
    }
    if (t < CS_) xcr[E_ + t] = (bf16)cond[(size_t)row * CS_ + t];
}

// ---------------- K-projection GEMM half: pure async16, K=4224, no remainder ----------------
__global__ __launch_bounds__(256) void k_gemm_k2(
    const bf16* __restrict__ A, const bf16* __restrict__ Bm,
    int koffB, bf16* __restrict__ Pout)
{
    __shared__ bf16 As[128][32];
    __shared__ bf16 Bs[128][32];
    int t = threadIdx.x;

    int pid = blockIdx.x;             // 576 = 8 gid * (8 mi * 9 ni)
    int gid = pid / 72;
    int rem = pid - gid * 72;
    int mi = gid * 8 + (rem & 7);
    int ni = rem >> 3;
    int m0 = mi << 7, n0 = ni << 7;

    int lane = t & 63, w = t >> 6;
    int wm = (w >> 1) * 64, wn = (w & 1) * 64;
    int lr = lane & 15, lq = lane >> 4;

    int row_i[2], seg_i[2];
#pragma unroll
    for (int i = 0; i < 2; ++i) { row_i[i] = (t + i * 256) >> 2; seg_i[i] = (t + i * 256) & 3; }

    v4f acc[4][4];
    v4f vzero = {0.f, 0.f, 0.f, 0.f};
#pragma unroll
    for (int mt = 0; mt < 4; ++mt)
#pragma unroll
        for (int nt = 0; nt < 4; ++nt) acc[mt][nt] = vzero;

    for (int kb = 0; kb < KH_ / 32; ++kb) {
        int k0 = kb << 5;
#pragma unroll
        for (int i = 0; i < 2; ++i) {
            async16(A + (size_t)(m0 + row_i[i]) * KH_ + k0 + seg_i[i] * 8,
                    &As[0][0] + (t + i * 256) * 8);
            async16(Bm + (size_t)(n0 + row_i[i]) * KB2_ + koffB + k0 + seg_i[i] * 8,
                    &Bs[0][0] + (t + i * 256) * 8);
        }
        __syncthreads();
        v8bf af[4], bfr[4];
#pragma unroll
        for (int mt = 0; mt < 4; ++mt) af[mt]  = *(const v8bf*)(&As[wm + mt * 16 + lr][lq * 8]);
#pragma unroll
        for (int nt = 0; nt < 4; ++nt) bfr[nt] = *(const v8bf*)(&Bs[wn + nt * 16 + lr][lq * 8]);
#pragma unroll
        for (int mt = 0; mt < 4; ++mt)
#pragma unroll
            for (int nt = 0; nt < 4; ++nt)
                acc[mt][nt] = mfma16(af[mt], bfr[nt], acc[mt][nt]);
        __syncthreads();
    }

#pragma unroll
    for (int mt = 0; mt < 4; ++mt)
#pragma unroll
        for (int reg = 0; reg < 4; ++reg) {
            int grow = m0 + wm + mt * 16 + lq * 4 + reg;
#pragma unroll
            for (int nt = 0; nt < 4; ++nt) {
                int gcol = n0 + wn + nt * 16 + lr;
                if (gcol < D_)
                    Pout[(size_t)grow * D_ + gcol] = (bf16)acc[mt][nt][reg];
            }
        }
}

// ---------------- combine K partials + cond*bk bias -> kp padded layout ----------------
__global__ __launch_bounds__(256) void k_comb_k(
    const bf16* __restrict__ P0, const bf16* __restrict__ P1,
    const float* __restrict__ condw, const float* __restrict__ bkp,
    bf16* __restrict__ kp)
{
    int idx = blockIdx.x * 256 + threadIdx.x;   // 8192*1040
    int m = idx / 1040, n = idx - m * 1040;
    float v = (float)P0[idx] + (float)P1[idx];
#pragma unroll
    for (int c = 0; c < NC_; ++c)
        v += condw[(size_t)m * CS_ + c] * bkp[(size_t)c * D_ + n];
    int h = n / 65, d = n - h * 65;
    int b = m >> 11, s = m & 2047;
    kp[(((size_t)(b * 16 + h)) * S_ + s) * 96 + d] = (bf16)v;
}

// ---------------- generic GEMM w/ epilogues (QV, O, FF1, FF2) ----------------
#define EP_QV  0
#define EP_O   1
#define EP_FF1 2
#define EP_FF2 3

template<int EP>
__global__ __launch_bounds__(256) void k_gemm(
    const bf16* __restrict__ A, const bf16* __restrict__ Bm,
    const float* __restrict__ bias, const float* __restrict__ bias2,
    int M, int N, int K, int lda, int ldb, int nbn,
    bf16* __restrict__ Cb, float* __restrict__ Cf, int ldc,
    const bf16* __restrict__ res, int ldres, bf16* __restrict__ Cb2)
{
    __shared__ bf16 As[128][32];
    __shared__ bf16 Bs[128][32];
    int t = threadIdx.x;

    int pid = blockIdx.x;
    int nig = 8 * nbn;
    int gid = pid / nig;
    int rem = pid - gid * nig;
    int mi = gid * 8 + (rem & 7);
    int ni = rem >> 3;
    int m0 = mi << 7, n0 = ni << 7;

    int lane = t & 63, w = t >> 6;
    int wm = (w >> 1) * 64, wn = (w & 1) * 64;
    int lr = lane & 15, lq = lane >> 4;

    int row_i[2], seg_i[2];
#pragma unroll
    for (int i = 0; i < 2; ++i) { row_i[i] = (t + i * 256) >> 2; seg_i[i] = (t + i * 256) & 3; }

    v4f acc[4][4];
    v4f vzero = {0.f, 0.f, 0.f, 0.f};
#pragma unroll
    for (int mt = 0; mt < 4; ++mt)
#pragma unroll
        for (int nt = 0; nt < 4; ++nt) acc[mt][nt] = vzero;

    const int KF = K >> 5;
    const bool KR = (K & 31) != 0;

    for (int kb = 0; kb < KF; ++kb) {
        int k0 = kb << 5;
#pragma unroll
        for (int i = 0; i < 2; ++i) {
            async16(A + (size_t)(m0 + row_i[i]) * lda + k0 + seg_i[i] * 8,
                    &As[0][0] + (t + i * 256) * 8);
            async16(Bm + (size_t)(n0 + row_i[i]) * ldb + k0 + seg_i[i] * 8,
                    &Bs[0][0] + (t + i * 256) * 8);
        }
        __syncthreads();
        v8bf af[4], bfr[4];
#pragma unroll
        for (int mt = 0; mt < 4; ++mt) af[mt]  = *(const v8bf*)(&As[wm + mt * 16 + lr][lq * 8]);
#pragma unroll
        for (int nt = 0; nt < 4; ++nt) bfr[nt] = *(const v8bf*)(&Bs[wn + nt * 16 + lr][lq * 8]);
#pragma unroll
        for (int mt = 0; mt < 4; ++mt)
#pragma unroll
            for (int nt = 0; nt < 4; ++nt)
                acc[mt][nt] = mfma16(af[mt], bfr[nt], acc[mt][nt]);
        __syncthreads();
    }
    if (KR) {
        int k0 = KF << 5;
#pragma unroll
        for (int i = 0; i < 2; ++i) {
            int gk = k0 + seg_i[i] * 8;
            uint4 val = {0u, 0u, 0u, 0u};
            if (gk + 8 <= K) val = *(const uint4*)(A + (size_t)(m0 + row_i[i]) * lda + gk);
            *(uint4*)(&As[row_i[i]][seg_i[i] * 8]) = val;
            uint4 bv = {0u, 0u, 0u, 0u};
            int gn = n0 + row_i[i];
            if (gn < N && gk + 8 <= K) bv = *(const uint4*)(Bm + (size_t)gn * ldb + gk);
            *(uint4*)(&Bs[row_i[i]][seg_i[i] * 8]) = bv;
        }
        __syncthreads();
        v8bf af[4], bfr[4];
#pragma unroll
        for (int mt = 0; mt < 4; ++mt) af[mt]  = *(const v8bf*)(&As[wm + mt * 16 + lr][lq * 8]);
#pragma unroll
        for (int nt = 0; nt < 4; ++nt) bfr[nt] = *(const v8bf*)(&Bs[wn + nt * 16 + lr][lq * 8]);
#pragma unroll
        for (int mt = 0; mt < 4; ++mt)
#pragma unroll
            for (int nt = 0; nt < 4; ++nt)
                acc[mt][nt] = mfma16(af[mt], bfr[nt], acc[mt][nt]);
        __syncthreads();
    }

#pragma unroll
    for (int mt = 0; mt < 4; ++mt) {
#pragma unroll
        for (int reg = 0; reg < 4; ++reg) {
            int grow = m0 + wm + mt * 16 + lq * 4 + reg;
#pragma unroll
            for (int nt = 0; nt < 4; ++nt) {
                int gcol = n0 + wn + nt * 16 + lr;
                float vacc = acc[mt][nt][reg];
                if constexpr (EP == EP_QV) {
                    if (gcol < D_) { // Q -> qp padded layout, pre-scaled by log2e/sqrt(65)
                        float o = (vacc + bias[gcol]) * 0.1789442960f;
                        int h = gcol / 65, d = gcol - h * 65;
                        int b = grow >> 11, s = grow & 2047;
                        Cb[(((size_t)(b * 16 + h)) * S_ + s) * 96 + d] = (bf16)o;
                    } else if (gcol < 2 * D_) { // V -> vb row-major
                        int col = gcol - D_;
                        Cb2[(size_t)grow * D_ + col] = (bf16)(vacc + bias2[col]);
                    }
                } else if constexpr (EP == EP_O) {
                    float o = vacc + bias[gcol] + (float)res[(size_t)grow * ldres + gcol];
                    Cb[(size_t)grow * ldc + gcol] = (bf16)o;
                } else if constexpr (EP == EP_FF1) {
                    float o = vacc + bias[gcol];
                    Cb[(size_t)grow * ldc + gcol] = (bf16)fmaxf(o, 0.f);
                } else { // EP_FF2 -> f32 z with bias + residual
                    Cf[(size_t)grow * ldc + gcol] =
                        vacc + bias[gcol] + (float)res[(size_t)grow * ldres + gcol];
                }
            }
        }
    }
}

// ---------------- transpose v (M x D bf16) into vt [bh][d(80)][s] ----------------
__global__ __launch_bounds__(256) void k_transpose_v(
    const bf16* __restrict__ v, bf16* __restrict__ vt)
{
    int bh = blockIdx.y, s0 = blockIdx.x * 64;
    int b = bh >> 4, h = bh & 15;
    __shared__ bf16 tile[80][65];
#pragma unroll
    for (int i = 0; i < 20; ++i) {
        int idx = threadIdx.x + i * 256;
        int d = idx % 80, sl = idx / 80;
        bf16 val = (bf16)0.f;
        if (d < DH_) val = v[((size_t)b * S_ + s0 + sl) * D_ + h * DH_ + d];
        tile[d][sl] = val;
    }
    __syncthreads();
#pragma unroll
    for (int i = 0; i < 20; ++i) {
        int idx = threadIdx.x + i * 256;
        int sl = idx % 64, d = idx / 64;
        vt[((size_t)bh * 80 + d) * S_ + s0 + sl] = tile[d][sl];
    }
}

// ---------------- flash attention ----------------
__global__ __launch_bounds__(256) void k_attn(
    const bf16* __restrict__ qp, const bf16* __restrict__ kp,
    const bf16* __restrict__ vt, bf16* __restrict__ o)
{
    int bh = blockIdx.y;
    int s0 = blockIdx.x * 64;
    int b = bh >> 4, h = bh & 15;
    int t = threadIdx.x, lane = t & 63, w = t >> 6;
    int lr = lane & 15, lq = lane >> 4;

    __shared__ bf16 Ks[64][104];
    __shared__ bf16 Vs[80][72];
    __shared__ bf16 QP[64 * 104];

    const bf16* qbase = qp + ((size_t)bh * S_ + s0) * 96;
#pragma unroll
    for (int i = 0; i < 3; ++i) {
        int idx = t + i * 256;
        int row = idx / 12, seg = idx % 12;
        *(uint4*)(&QP[row * 104 + seg * 8]) = *(const uint4*)(qbase + (size_t)row * 96 + seg * 8);
    }
    __syncthreads();
    v8bf qreg[3];
#pragma unroll
    for (int ks = 0; ks < 3; ++ks)
        qreg[ks] = *(const v8bf*)(&QP[(w * 16 + lr) * 104 + ks * 32 + lq * 8]);
    __syncthreads();

    bf16* Ps = &QP[w * (16 * 72)];

    float m_r[4], l_r[4];
    v4f o_acc[5];
    v4f vzero = {0.f, 0.f, 0.f, 0.f};
#pragma unroll
    for (int r = 0; r < 4; ++r) { m_r[r] = -1e30f; l_r[r] = 0.f; }
#pragma unroll
    for (int nt = 0; nt < 5; ++nt) o_acc[nt] = vzero;

    for (int kb = 0; kb < S_ / 64; ++kb) {
        const bf16* kbase = kp + ((size_t)bh * S_ + kb * 64) * 96;
#pragma unroll
        for (int i = 0; i < 3; ++i) {
            int idx = t + i * 256;
            int row = idx / 12, seg = idx % 12;
            *(uint4*)(&Ks[row][seg * 8]) = *(const uint4*)(kbase + (size_t)row * 96 + seg * 8);
        }
#pragma unroll
        for (int i = 0; i < 3; ++i) {
            int idx = t + i * 256;
            if (idx < 640) {
                int d = idx >> 3, seg = idx & 7;
                *(uint4*)(&Vs[d][seg * 8]) =
                    *(const uint4*)(vt + ((size_t)bh * 80 + d) * S_ + kb * 64 + seg * 8);
            }
        }
        __syncthreads();

        v4f sacc[4];
#pragma unroll
        for (int nt = 0; nt < 4; ++nt) sacc[nt] = vzero;
#pragma unroll
        for (int ks = 0; ks < 3; ++ks) {
#pragma unroll
            for (int nt = 0; nt < 4; ++nt) {
                v8bf bk2 = *(const v8bf*)(&Ks[nt * 16 + lr][ks * 32 + lq * 8]);
                sacc[nt] = mfma16(qreg[ks], bk2, sacc[nt]);
            }
        }

        float alpha[4];
#pragma unroll
        for (int r = 0; r < 4; ++r) {
            float mx = fmaxf(fmaxf(sacc[0][r], sacc[1][r]), fmaxf(sacc[2][r], sacc[3][r]));
#pragma unroll
            for (int off = 1; off < 16; off <<= 1) mx = fmaxf(mx, __shfl_xor(mx, off));
            float mnew = fmaxf(m_r[r], mx);
            alpha[r] = __builtin_amdgcn_exp2f(m_r[r] - mnew);
            float ps = 0.f;
#pragma unroll
            for (int nt = 0; nt < 4; ++nt) {
                float p = __builtin_amdgcn_exp2f(sacc[nt][r] - mnew);
                sacc[nt][r] = p;
                ps += p;
            }
#pragma unroll
            for (int off = 1; off < 16; off <<= 1) ps += __shfl_xor(ps, off);
            l_r[r] = l_r[r] * alpha[r] + ps;
            m_r[r] = mnew;
        }

#pragma unroll
        for (int nt = 0; nt < 4; ++nt)
#pragma unroll
            for (int r = 0; r < 4; ++r)
                Ps[(lq * 4 + r) * 72 + nt * 16 + lr] = (bf16)sacc[nt][r];
        asm volatile("s_waitcnt lgkmcnt(0)" ::: "memory");

#pragma unroll
        for (int nt = 0; nt < 5; ++nt)
#pragma unroll
            for (int r = 0; r < 4; ++r) o_acc[nt][r] *= alpha[r];

#pragma unroll
        for (int kt = 0; kt < 2; ++kt) {
            v8bf ap = *(const v8bf*)(&Ps[lr * 72 + kt * 32 + lq * 8]);
#pragma unroll
            for (int nt = 0; nt < 5; ++nt) {
                v8bf bv2 = *(const v8bf*)(&Vs[nt * 16 + lr][kt * 32 + lq * 8]);
                o_acc[nt] = mfma16(ap, bv2, o_acc[nt]);
            }
        }
        __syncthreads();
    }

    float inv[4];
#pragma unroll
    for (int r = 0; r < 4; ++r) inv[r] = 1.0f / l_r[r];
    int token = b * S_ + s0 + w * 16 + lq * 4;
#pragma unroll
    for (int nt = 0; nt < 5; ++nt) {
        int d = nt * 16 + lr;
        if (d < DH_) {
#pragma unroll
            for (int r = 0; r < 4; ++r)
                o[(size_t)(token + r) * D_ + h * DH_ + d] = (bf16)(o_acc[nt][r] * inv[r]);
        }
    }
}

// ---------------- final LayerNorm on z (f32) -> out f32 ----------------
__global__ __launch_bounds__(256) void k_ln_out(
    const float* __restrict__ z, const float* __restrict__ g,
    const float* __restrict__ bn, float* __restrict__ out)
{
    int row = blockIdx.x;
    int t = threadIdx.x;
    const float* zr = z + (size_t)row * E_;
    float4 v = *(const float4*)(zr + t * 4);
    float s = v.x + v.y + v.z + v.w;
    float ss = v.x * v.x + v.y * v.y + v.z * v.z + v.w * v.w;
#pragma unroll
    for (int off = 32; off; off >>= 1) {
        s  += __shfl_down(s, off);
        ss += __shfl_down(ss, off);
    }
    __shared__ float red[8];
    int wid = t >> 6;
    if ((t & 63) == 0) { red[wid] = s; red[4 + wid] = ss; }
    __syncthreads();
    float stot  = red[0] + red[1] + red[2] + red[3];
    float sstot = red[4] + red[5] + red[6] + red[7];
    float mean = stot * (1.0f / E_);
    float var  = sstot * (1.0f / E_) - mean * mean;
    float rs = rsqrtf(var + 1e-5f);
    float* outr = out + (size_t)row * E_;
    float vv[4] = {v.x, v.y, v.z, v.w};
#pragma unroll
    for (int j = 0; j < 4; ++j) {
        int i = t * 4 + j;
        outr[i] = ((vv[j] - mean) * rs) * g[i] + bn[i];
    }
}

// ---------------- launch ----------------
extern "C" void kernel_launch(void* const* d_in, const int* in_sizes, int n_in,
                              void* d_out, int out_size, void* d_ws, size_t ws_size,
                              hipStream_t stream) {
    const float* x    = (const float*)d_in[0];
    const float* cond = (const float*)d_in[1];
    const float* Wq   = (const float*)d_in[2];
    const float* bq   = (const float*)d_in[3];
    const float* Wv   = (const float*)d_in[4];
    const float* bv   = (const float*)d_in[5];
    const float* Wk   = (const float*)d_in[6];
    const float* bk   = (const float*)d_in[7];
    const float* Wo   = (const float*)d_in[8];
    const float* bo   = (const float*)d_in[9];
    const float* g1   = (const float*)d_in[10];
    const float* bn1  = (const float*)d_in[11];
    const float* g2   = (const float*)d_in[12];
    const float* bn2  = (const float*)d_in[13];
    const float* Wf1  = (const float*)d_in[14];
    const float* bf1  = (const float*)d_in[15];
    const float* Wf2  = (const float*)d_in[16];
    const float* bf2  = (const float*)d_in[17];
    float* out = (float*)d_out;

    char* ws = (char*)d_ws;
    bf16* Wqv_b = (bf16*)(ws + 0);            //  4,526,080
    bf16* Wo_b  = (bf16*)(ws + 4526080);      //  2,129,920 (1024 rows) -> 6,656,000
    bf16* Wf1_b = (bf16*)(ws + 6656000);      //  8,388,608 -> 15,044,608
    bf16* Wf2_b = (bf16*)(ws + 15044608);     //  8,388,608 -> 23,433,216
    bf16*  xc   = (bf16*)(ws + 23433216);     // 17,039,360 -> 40,472,576
    // K phase (dead after comb_k):
    bf16*  Bpk  = (bf16*)(ws + 40472576);     // 1152*8448*2 = 19,464,192 -> 59,936,768
    bf16*  Apk  = (bf16*)(ws + 59936768);     // 8192*4224*2 = 69,206,016 -> 129,142,784
    bf16*  P0k  = (bf16*)(ws + 129142784);    // 17,039,360 -> 146,182,144
    bf16*  P1k  = (bf16*)(ws + 146182144);    // 17,039,360 -> 163,221,504 (peak)
    // attention phase (aliases K-phase buffers):
    bf16*  qp   = (bf16*)(ws + 40472576);     // 25,165,824 -> 65,638,400
    bf16*  kp   = (bf16*)(ws + 65638400);     // 25,165,824 -> 90,804,224
    bf16*  vb   = (bf16*)(ws + 90804224);     // 17,039,360 -> 107,843,584 (hb post-attn)
    bf16*  hb   = (bf16*)(ws + 90804224);
    bf16*  vtb  = (bf16*)(ws + 107843584);    // 20,971,520 -> 128,815,104
    bf16*  ob   = (bf16*)(ws + 128815104);    // 17,039,360 -> 145,854,464
    // FF phase:
    bf16*  ff1  = (bf16*)(ws + 23433216);     // 67,108,864 -> 90,542,080 (< hb)
    float* zb   = (float*)(ws + 107843584);   // 33,554,432 -> 141,398,016

    k_cvt<<<(1081600 / 4 + 255) / 256, 256, 0, stream>>>(Wq, Wqv_b, 1081600);
    k_cvt<<<(1081600 / 4 + 255) / 256, 256, 0, stream>>>(Wv, Wqv_b + 1081600, 1081600);
    k_cvt<<<(1064960 / 4 + 255) / 256, 256, 0, stream>>>(Wo, Wo_b, 1064960);
    k_cvt<<<(4194304 / 4 + 255) / 256, 256, 0, stream>>>(Wf1, Wf1_b, 4194304);
    k_cvt<<<(4194304 / 4 + 255) / 256, 256, 0, stream>>>(Wf2, Wf2_b, 4194304);

    k_ln_concat<<<M_, 256, 0, stream>>>(x, cond, g1, bn1, xc);

    // K projection: B' repack, then two half-c passes over a shared A' buffer
    k_build_bk<<<dim3((1040 * 130 + 255) / 256, 8), 256, 0, stream>>>(Wk, Bpk);
    k_scale_a<<<(M_ * 132) / 256, 256, 0, stream>>>(xc, cond, 0, Apk);
    k_gemm_k2<<<576, 256, 0, stream>>>(Apk, Bpk, 0, P0k);
    k_scale_a<<<(M_ * 132) / 256, 256, 0, stream>>>(xc, cond, 4, Apk);
    k_gemm_k2<<<576, 256, 0, stream>>>(Apk, Bpk, KH_, P1k);

    k_zero_pads<<<4096, 256, 0, stream>>>(qp, kp);
    k_comb_k<<<(M_ * D_) / 256, 256, 0, stream>>>(P0k, P1k, cond, bk, kp);

    // fused Q+V (N=2080 over 17 n-blocks)
    k_gemm<EP_QV><<<64 * 17, 256, 0, stream>>>(xc, Wqv_b, bq, bv, M_, 2 * D_, D_, D_, D_, 17,
                                               qp, nullptr, 0, nullptr, 0, vb);

    k_transpose_v<<<dim3(S_ / 64, 64), 256, 0, stream>>>(vb, vtb);
    k_attn<<<dim3(S_ / 64, 64), 256, 0, stream>>>(qp, kp, vtb, ob);

    k_gemm<EP_O><<<64 * 8, 256, 0, stream>>>(ob, Wo_b, bo, nullptr, M_, E_, D_, D_, D_, 8,
                                             hb, nullptr, E_, xc, D_, nullptr);
    k_gemm<EP_FF1><<<64 * 32, 256, 0, stream>>>(hb, Wf1_b, bf1, nullptr, M_, DFF_, E_, E_, E_, 32,
                                                ff1, nullptr, DFF_, nullptr, 0, nullptr);
    k_gemm<EP_FF2><<<64 * 8, 256, 0, stream>>>(ff1, Wf2_b, bf2, nullptr, M_, E_, DFF_, DFF_, DFF_, 8,
                                               nullptr, zb, E_, hb, E_, nullptr);

    k_ln_out<<<M_, 256, 0, stream>>>(zb, g2, bn2, out);
}